// Round 8
// baseline (182.755 us; speedup 1.0000x reference)
//
#include <hip/hip_runtime.h>
#include <hip/hip_bf16.h>

#define BATCH 4
#define IC 64
#define OC 128
#define HSZ 56
#define WSZ 56
#define HW 3136            // 56*56
#define PW 58              // padded width (1 + 56 + 1)
#define PPIX 3364          // 58*58 padded pixels
#define KTOT 576           // 9 taps * 64 ch
#define GROWS 64           // leading guard rows (zero) per image
#define XROWS 3584         // per-image alloc rows: 64 guard + 3520 (zero tail)

typedef __attribute__((ext_vector_type(8))) short bf16x8;
typedef __attribute__((ext_vector_type(4))) float f32x4;

// ---- prep: x -> zero-padded [pix][ch] bf16 (xpad), W -> Wb[o][k] bf16 ----
__global__ __launch_bounds__(256) void prep_kernel(
    const float* __restrict__ x,            // [B][64][3136] f32
    const float* __restrict__ W,            // [128][64][3][3] f32
    unsigned short* __restrict__ Wb,        // [128][576] bf16
    unsigned short* __restrict__ xpad)      // [B][3584][64] bf16
{
    const int blk = blockIdx.x;
    const int t   = threadIdx.x;

    if (blk < BATCH * 56) {
        const int b    = blk / 56;
        const int tile = blk - b * 56;
        const int a    = tile * 64 + (t & 63);    // alloc row 0..3583
        const int chg  = t >> 6;                  // 0..3 (16 ch each)
        const int pp   = a - GROWS;               // padded pixel index
        int r = 1, c = 1;
        bool inb = false;
        if (pp >= 0 && pp < PPIX) {
            r = pp / PW;
            c = pp - r * PW;
            inb = (r >= 1) && (r <= HSZ) && (c >= 1) && (c <= WSZ);
        }
        const int sp = (r - 1) * WSZ + (c - 1);   // source pixel (valid iff inb)
        const float* xb = x + (size_t)b * IC * HW;

        unsigned short __attribute__((aligned(16))) v[16];
#pragma unroll
        for (int i = 0; i < 16; ++i) {
            const int ch = chg * 16 + i;
            float f = inb ? xb[ch * HW + sp] : 0.0f;
            __hip_bfloat16 h = __float2bfloat16(f);
            v[i] = *reinterpret_cast<unsigned short*>(&h);
        }
        unsigned short* dst = xpad + ((size_t)b * XROWS + a) * IC + chg * 16;
        *reinterpret_cast<uint4*>(dst)     = *reinterpret_cast<uint4*>(&v[0]);
        *reinterpret_cast<uint4*>(dst + 8) = *reinterpret_cast<uint4*>(&v[8]);
    } else {
        const int j = (blk - BATCH * 56) * 256 + t;    // 0..73727
        if (j < OC * KTOT) {
            const int o   = j / KTOT;
            const int k   = j - o * KTOT;
            const int tap = k >> 6;
            const int ch  = k & 63;
            __hip_bfloat16 h = __float2bfloat16(W[(o * IC + ch) * 9 + tap]);
            Wb[j] = *reinterpret_cast<unsigned short*>(&h);
        }
    }
}

// ---- conv: implicit GEMM, wave tile 64px x 64oc (M_rep=4, N_rep=4) ----
__global__ __launch_bounds__(128) void conv_mfma_kernel(
    const unsigned short* __restrict__ xpad, // [B][3584][64] bf16
    const unsigned short* __restrict__ Wb,   // [128][576] bf16
    const float* __restrict__ bias,          // [128] f32
    float* __restrict__ out)                 // [B][128][3136] f32
{
    const int t    = threadIdx.x;
    const int lane = t & 63;
    const int wv   = t >> 6;                 // wave 0..1
    const int lrow = lane & 15;              // A-row (pixel) / B-col (oc)
    const int lk   = lane >> 4;              // k-chunk 0..3

    const int pw0 = blockIdx.x * 128 + wv * 64;   // wave's first padded pixel
    const int og  = blockIdx.y;
    const int b   = blockIdx.z;

    const unsigned short* xb = xpad + ((size_t)b * XROWS + GROWS) * IC;
    const unsigned short* xa0 = xb + (size_t)(pw0 +  0 + lrow) * IC + lk * 8;
    const unsigned short* xa1 = xb + (size_t)(pw0 + 16 + lrow) * IC + lk * 8;
    const unsigned short* xa2 = xb + (size_t)(pw0 + 32 + lrow) * IC + lk * 8;
    const unsigned short* xa3 = xb + (size_t)(pw0 + 48 + lrow) * IC + lk * 8;
    const unsigned short* wbp = Wb + (size_t)(og * 64 + lrow) * KTOT + lk * 8;

    f32x4 acc[4][4] = {};

#pragma unroll
    for (int dh = -1; dh <= 1; ++dh) {
#pragma unroll
        for (int dw = -1; dw <= 1; ++dw) {
            const int toff = dh * PW + dw;               // flat tap offset
            const int tap  = (dh + 1) * 3 + (dw + 1);
#pragma unroll
            for (int half = 0; half < 2; ++half) {
                const int ao = toff * IC + half * 32;
                bf16x8 a0 = *reinterpret_cast<const bf16x8*>(xa0 + ao);
                bf16x8 a1 = *reinterpret_cast<const bf16x8*>(xa1 + ao);
                bf16x8 a2 = *reinterpret_cast<const bf16x8*>(xa2 + ao);
                bf16x8 a3 = *reinterpret_cast<const bf16x8*>(xa3 + ao);
                const unsigned short* wp = wbp + tap * 64 + half * 32;
                bf16x8 b0 = *reinterpret_cast<const bf16x8*>(wp);
                bf16x8 b1 = *reinterpret_cast<const bf16x8*>(wp + 16 * KTOT);
                bf16x8 b2 = *reinterpret_cast<const bf16x8*>(wp + 32 * KTOT);
                bf16x8 b3 = *reinterpret_cast<const bf16x8*>(wp + 48 * KTOT);
                acc[0][0] = __builtin_amdgcn_mfma_f32_16x16x32_bf16(a0, b0, acc[0][0], 0, 0, 0);
                acc[0][1] = __builtin_amdgcn_mfma_f32_16x16x32_bf16(a0, b1, acc[0][1], 0, 0, 0);
                acc[0][2] = __builtin_amdgcn_mfma_f32_16x16x32_bf16(a0, b2, acc[0][2], 0, 0, 0);
                acc[0][3] = __builtin_amdgcn_mfma_f32_16x16x32_bf16(a0, b3, acc[0][3], 0, 0, 0);
                acc[1][0] = __builtin_amdgcn_mfma_f32_16x16x32_bf16(a1, b0, acc[1][0], 0, 0, 0);
                acc[1][1] = __builtin_amdgcn_mfma_f32_16x16x32_bf16(a1, b1, acc[1][1], 0, 0, 0);
                acc[1][2] = __builtin_amdgcn_mfma_f32_16x16x32_bf16(a1, b2, acc[1][2], 0, 0, 0);
                acc[1][3] = __builtin_amdgcn_mfma_f32_16x16x32_bf16(a1, b3, acc[1][3], 0, 0, 0);
                acc[2][0] = __builtin_amdgcn_mfma_f32_16x16x32_bf16(a2, b0, acc[2][0], 0, 0, 0);
                acc[2][1] = __builtin_amdgcn_mfma_f32_16x16x32_bf16(a2, b1, acc[2][1], 0, 0, 0);
                acc[2][2] = __builtin_amdgcn_mfma_f32_16x16x32_bf16(a2, b2, acc[2][2], 0, 0, 0);
                acc[2][3] = __builtin_amdgcn_mfma_f32_16x16x32_bf16(a2, b3, acc[2][3], 0, 0, 0);
                acc[3][0] = __builtin_amdgcn_mfma_f32_16x16x32_bf16(a3, b0, acc[3][0], 0, 0, 0);
                acc[3][1] = __builtin_amdgcn_mfma_f32_16x16x32_bf16(a3, b1, acc[3][1], 0, 0, 0);
                acc[3][2] = __builtin_amdgcn_mfma_f32_16x16x32_bf16(a3, b2, acc[3][2], 0, 0, 0);
                acc[3][3] = __builtin_amdgcn_mfma_f32_16x16x32_bf16(a3, b3, acc[3][3], 0, 0, 0);
            }
        }
    }

    // Epilogue: predicated scalar stores (pad pixels discarded).
#pragma unroll
    for (int bg = 0; bg < 4; ++bg) {
        const int oc = og * 64 + bg * 16 + lrow;
        const float bv = bias[oc];
        float* ob = out + ((size_t)(b * OC + oc)) * HW;
#pragma unroll
        for (int mg = 0; mg < 4; ++mg) {
            const int pbase = pw0 + mg * 16 + 4 * lk;
#pragma unroll
            for (int j = 0; j < 4; ++j) {
                const int p = pbase + j;
                const int r = p / PW;
                const int c = p - r * PW;
                if (r >= 1 && r <= HSZ && c >= 1 && c <= WSZ)
                    ob[(r - 1) * WSZ + (c - 1)] = acc[mg][bg][j] + bv;
            }
        }
    }
}

extern "C" void kernel_launch(void* const* d_in, const int* in_sizes, int n_in,
                              void* d_out, int out_size, void* d_ws, size_t ws_size,
                              hipStream_t stream) {
    const float* x    = (const float*)d_in[0];
    const float* W    = (const float*)d_in[1];
    const float* bias = (const float*)d_in[2];
    float* out        = (float*)d_out;

    unsigned short* Wb   = (unsigned short*)d_ws;                    // 147456 B
    unsigned short* xpad = (unsigned short*)((char*)d_ws + 147456);  // 4*3584*64*2 B

    prep_kernel<<<BATCH * 56 + (OC * KTOT + 255) / 256, 256, 0, stream>>>(x, W, Wb, xpad);

    dim3 grid(27, 2, BATCH);   // 27 tiles x 128 px = 3456 >= 3364 padded pixels

    // MEASUREMENT ROUND: conv launched 8x (idempotent — same inputs -> same out).
    // T = prep + 8*conv + overhead; with R7's T0 = prep + conv + overhead = 34.5us,
    // conv = (T - T0) / 7. Deterministic under graph replay.
#pragma unroll
    for (int rep = 0; rep < 8; ++rep)
        conv_mfma_kernel<<<grid, 128, 0, stream>>>(xpad, Wb, bias, out);
}

// Round 9
// 32.576 us; speedup vs baseline: 5.6101x; 5.6101x over previous
//
#include <hip/hip_runtime.h>
#include <hip/hip_bf16.h>

#define BATCH 4
#define IC 64
#define OC 128
#define HSZ 56
#define WSZ 56
#define HW 3136            // 56*56
#define PW 58              // padded width (1 + 56 + 1)
#define PPIX 3364          // 58*58 padded pixels
#define KTOT 576           // 9 taps * 64 ch
#define GROWS 64           // leading guard rows (zero) per image
#define XROWS 3584         // per-image alloc rows: 64 guard + 3520 (zero tail)

typedef __attribute__((ext_vector_type(8))) short bf16x8;
typedef __attribute__((ext_vector_type(4))) float f32x4;

// ---- prep: x -> zero-padded [pix][ch] bf16 (xpad), W -> Wb[o][k] bf16 ----
__global__ __launch_bounds__(256) void prep_kernel(
    const float* __restrict__ x,            // [B][64][3136] f32
    const float* __restrict__ W,            // [128][64][3][3] f32
    unsigned short* __restrict__ Wb,        // [128][576] bf16
    unsigned short* __restrict__ xpad)      // [B][3584][64] bf16
{
    const int blk = blockIdx.x;
    const int t   = threadIdx.x;

    if (blk < BATCH * 56) {
        const int b    = blk / 56;
        const int tile = blk - b * 56;
        const int a    = tile * 64 + (t & 63);    // alloc row 0..3583
        const int chg  = t >> 6;                  // 0..3 (16 ch each)
        const int pp   = a - GROWS;               // padded pixel index
        int r = 1, c = 1;
        bool inb = false;
        if (pp >= 0 && pp < PPIX) {
            r = pp / PW;
            c = pp - r * PW;
            inb = (r >= 1) && (r <= HSZ) && (c >= 1) && (c <= WSZ);
        }
        const int sp = (r - 1) * WSZ + (c - 1);   // source pixel (valid iff inb)
        const float* xb = x + (size_t)b * IC * HW;

        unsigned short __attribute__((aligned(16))) v[16];
#pragma unroll
        for (int i = 0; i < 16; ++i) {
            const int ch = chg * 16 + i;
            float f = inb ? xb[ch * HW + sp] : 0.0f;
            __hip_bfloat16 h = __float2bfloat16(f);
            v[i] = *reinterpret_cast<unsigned short*>(&h);
        }
        unsigned short* dst = xpad + ((size_t)b * XROWS + a) * IC + chg * 16;
        *reinterpret_cast<uint4*>(dst)     = *reinterpret_cast<uint4*>(&v[0]);
        *reinterpret_cast<uint4*>(dst + 8) = *reinterpret_cast<uint4*>(&v[8]);
    } else {
        const int j = (blk - BATCH * 56) * 256 + t;    // 0..73727
        if (j < OC * KTOT) {
            const int o   = j / KTOT;
            const int k   = j - o * KTOT;
            const int tap = k >> 6;
            const int ch  = k & 63;
            __hip_bfloat16 h = __float2bfloat16(W[(o * IC + ch) * 9 + tap]);
            Wb[j] = *reinterpret_cast<unsigned short*>(&h);
        }
    }
}

// ---- conv: implicit GEMM, wave tile 32px x 32oc (M_rep=2, N_rep=2) ----
// 1728 waves total (~6.8/CU) for latency hiding. Block 256 thr = 4 waves:
// wave w: pixel group (w&1), oc group (w>>1). Block covers 64px x 64oc.
__global__ __launch_bounds__(256) void conv_mfma_kernel(
    const unsigned short* __restrict__ xpad, // [B][3584][64] bf16
    const unsigned short* __restrict__ Wb,   // [128][576] bf16
    const float* __restrict__ bias,          // [128] f32
    float* __restrict__ out)                 // [B][128][3136] f32
{
    const int t    = threadIdx.x;
    const int lane = t & 63;
    const int wv   = t >> 6;                 // wave 0..3
    const int lrow = lane & 15;              // A-row (pixel) / B-col (oc)
    const int lk   = lane >> 4;              // k-chunk 0..3

    const int pw0 = blockIdx.x * 64 + (wv & 1) * 32;       // wave's first padded pixel
    const int oc0 = blockIdx.y * 64 + (wv >> 1) * 32;      // wave's first out channel
    const int b   = blockIdx.z;

    const unsigned short* xb = xpad + ((size_t)b * XROWS + GROWS) * IC;
    const unsigned short* xa0 = xb + (size_t)(pw0 +  0 + lrow) * IC + lk * 8;
    const unsigned short* xa1 = xb + (size_t)(pw0 + 16 + lrow) * IC + lk * 8;
    const unsigned short* wbp = Wb + (size_t)(oc0 + lrow) * KTOT + lk * 8;

    f32x4 acc[2][2] = {};

#pragma unroll
    for (int dh = -1; dh <= 1; ++dh) {
#pragma unroll
        for (int dw = -1; dw <= 1; ++dw) {
            const int toff = dh * PW + dw;               // flat tap offset
            const int tap  = (dh + 1) * 3 + (dw + 1);
#pragma unroll
            for (int half = 0; half < 2; ++half) {
                const int ao = toff * IC + half * 32;
                bf16x8 a0 = *reinterpret_cast<const bf16x8*>(xa0 + ao);
                bf16x8 a1 = *reinterpret_cast<const bf16x8*>(xa1 + ao);
                const unsigned short* wp = wbp + tap * 64 + half * 32;
                bf16x8 b0 = *reinterpret_cast<const bf16x8*>(wp);
                bf16x8 b1 = *reinterpret_cast<const bf16x8*>(wp + 16 * KTOT);
                acc[0][0] = __builtin_amdgcn_mfma_f32_16x16x32_bf16(a0, b0, acc[0][0], 0, 0, 0);
                acc[0][1] = __builtin_amdgcn_mfma_f32_16x16x32_bf16(a0, b1, acc[0][1], 0, 0, 0);
                acc[1][0] = __builtin_amdgcn_mfma_f32_16x16x32_bf16(a1, b0, acc[1][0], 0, 0, 0);
                acc[1][1] = __builtin_amdgcn_mfma_f32_16x16x32_bf16(a1, b1, acc[1][1], 0, 0, 0);
            }
        }
    }

    // Epilogue: predicated scalar stores (pad pixels discarded).
    // D layout: pixel = pw0 + mg*16 + 4*lk + j, oc = oc0 + bg*16 + lrow.
#pragma unroll
    for (int bg = 0; bg < 2; ++bg) {
        const int oc = oc0 + bg * 16 + lrow;
        const float bv = bias[oc];
        float* ob = out + ((size_t)(b * OC + oc)) * HW;
#pragma unroll
        for (int mg = 0; mg < 2; ++mg) {
            const int pbase = pw0 + mg * 16 + 4 * lk;
#pragma unroll
            for (int j = 0; j < 4; ++j) {
                const int p = pbase + j;
                const int r = p / PW;
                const int c = p - r * PW;
                if (r >= 1 && r <= HSZ && c >= 1 && c <= WSZ)
                    ob[(r - 1) * WSZ + (c - 1)] = acc[mg][bg][j] + bv;
            }
        }
    }
}

extern "C" void kernel_launch(void* const* d_in, const int* in_sizes, int n_in,
                              void* d_out, int out_size, void* d_ws, size_t ws_size,
                              hipStream_t stream) {
    const float* x    = (const float*)d_in[0];
    const float* W    = (const float*)d_in[1];
    const float* bias = (const float*)d_in[2];
    float* out        = (float*)d_out;

    unsigned short* Wb   = (unsigned short*)d_ws;                    // 147456 B
    unsigned short* xpad = (unsigned short*)((char*)d_ws + 147456);  // 4*3584*64*2 B

    prep_kernel<<<BATCH * 56 + (OC * KTOT + 255) / 256, 256, 0, stream>>>(x, W, Wb, xpad);

    dim3 grid(54, 2, BATCH);   // 54 x 64px = 3456 >= 3364 padded pixels; 432 blocks, 1728 waves
    conv_mfma_kernel<<<grid, 256, 0, stream>>>(xpad, Wb, bias, out);
}